// Round 1
// baseline (92.408 us; speedup 1.0000x reference)
//
#include <hip/hip_runtime.h>

#define B_ 4
#define N_ 8192
#define M_ 2048
#define K_ 32
#define C_ 64
#define PTS 8
#define THREADS 256

__device__ __forceinline__ float clampf(float x, float lo, float hi) {
    return fminf(fmaxf(x, lo), hi);
}

__global__ __launch_bounds__(THREADS) void fuzzy_kernel(
    const float* __restrict__ database,
    const float* __restrict__ query,
    const int*   __restrict__ nn_index,
    const float* __restrict__ nn_dist,
    const float* __restrict__ feats,
    const float* __restrict__ filt,
    float*       __restrict__ out)
{
    // Filter table transposed: Wp[q][c][r], q = bin>>1 (0..7), r = bin&1.
    // Lane c reads float2 at Wp + q*128 + c*2  -> stride-2 dword b64, conflict-free.
    __shared__ float  Wp[8 * C_ * 2];
    __shared__ float4 c03[PTS][K_];     // corners 0..3 (r = r_c group)
    __shared__ float4 c47[PTS][K_];     // corners 4..7 (r = r_c1 group)
    __shared__ unsigned meta[PTS][K_];  // packed q0..q3 (3b each), r_fl (1b), bidx (15b)

    const int tid = threadIdx.x;

    // ---- load filter weights (16x64) into LDS, transposed ----
    #pragma unroll
    for (int i = tid; i < 16 * C_; i += THREADS) {
        int t = i >> 6;       // bin 0..15
        int c = i & 63;       // channel
        Wp[(t >> 1) * (C_ * 2) + c * 2 + (t & 1)] = filt[i];
    }

    // ---- Phase A: one thread per (point-in-block, k) ----
    {
        const int pin = tid >> 5;                  // 0..7
        const int k   = tid & 31;                  // 0..31
        const int p   = blockIdx.x * PTS + pin;    // global point 0..8191
        const int b   = p >> 11;                   // p / M_
        const float qx = query[p * 3 + 0];
        const float qy = query[p * 3 + 1];
        const float qz = query[p * 3 + 2];
        const int   idx  = nn_index[p * K_ + k];
        const float dist = nn_dist[p * K_ + k];
        const int   bidx = b * N_ + idx;           // feature row, 15 bits
        const float x = database[bidx * 3 + 0] - qx;
        const float y = database[bidx * 3 + 1] - qy;
        const float z = database[bidx * 3 + 2] - qz;

        const float PI_F = 3.14159265358979323846f;
        const float SC   = 0.636619772367581343f;  // 2/pi == N_AZ/(2pi) == N_EL/pi
        float azim = atan2f(y, x) + PI_F;
        float elev = acosf(clampf(z / (dist + 1e-8f), -1.0f, 1.0f));
        float a_bin = azim * SC;                   // [0,4]
        float e_bin = elev * SC;                   // [0,2]
        float r_bin = clampf(dist * 20.0f, 0.0f, 1.999999f);
        float a_fl = floorf(a_bin), e_fl = floorf(e_bin), r_fl = floorf(r_bin);
        float a_fr = a_bin - a_fl, e_fr = e_bin - e_fl, r_fr = r_bin - r_fl;
        float ai = 1.0f - a_fr, ei = 1.0f - e_fr, ri = 1.0f - r_fr;
        int a_i = (int)a_fl, e_i = (int)e_fl, r_i = (int)r_fl;
        int a0 = a_i & 3, a1 = (a_i + 1) & 3;
        int ec = e_i < 1 ? e_i : 1;                // e_c;  e_c1 == 1 always (N_EL=2)
        // bin t = (a%4)*4 + e*2 + r ; q = t>>1 = (a%4)*2 + e ; r_c1 == 1 always (N_RAD=2)
        unsigned m = (unsigned)(a0 * 2 + ec)
                   | ((unsigned)(a1 * 2 + ec) << 3)
                   | ((unsigned)(a0 * 2 + 1)  << 6)
                   | ((unsigned)(a1 * 2 + 1)  << 9)
                   | ((unsigned)r_i << 12)
                   | ((unsigned)bidx << 13);
        meta[pin][k] = m;
        c03[pin][k] = make_float4(ai * ei * ri,  a_fr * ei * ri,  ai * e_fr * ri,  a_fr * e_fr * ri);
        c47[pin][k] = make_float4(ai * ei * r_fr, a_fr * ei * r_fr, ai * e_fr * r_fr, a_fr * e_fr * r_fr);
    }
    __syncthreads();

    // ---- Phase B: wave w handles points 2w, 2w+1; lane = channel ----
    const int wave = tid >> 6;
    const int lane = tid & 63;
    const int pinA = wave * 2;
    const int pinB = pinA + 1;
    const int pA   = blockIdx.x * PTS + pinA;
    float accA = 0.0f, accB = 0.0f;
    const float* WpL = Wp + lane * 2;

    #pragma unroll 8
    for (int k = 0; k < K_; ++k) {
        const unsigned mA = meta[pinA][k];
        const unsigned mB = meta[pinB][k];
        const float4 cA0 = c03[pinA][k];
        const float4 cA1 = c47[pinA][k];
        const float4 cB0 = c03[pinB][k];
        const float4 cB1 = c47[pinB][k];
        const float nfA = feats[((mA >> 13) << 6) + lane];
        const float nfB = feats[((mB >> 13) << 6) + lane];

        {
            const float2 w0 = *(const float2*)(WpL + ((mA      ) & 7u) * 128);
            const float2 w1 = *(const float2*)(WpL + ((mA >> 3 ) & 7u) * 128);
            const float2 w2 = *(const float2*)(WpL + ((mA >> 6 ) & 7u) * 128);
            const float2 w3 = *(const float2*)(WpL + ((mA >> 9 ) & 7u) * 128);
            const bool sr = (mA >> 12) & 1u;
            float e;
            e  = cA0.x * (sr ? w0.y : w0.x) + cA1.x * w0.y;
            e += cA0.y * (sr ? w1.y : w1.x) + cA1.y * w1.y;
            e += cA0.z * (sr ? w2.y : w2.x) + cA1.z * w2.y;
            e += cA0.w * (sr ? w3.y : w3.x) + cA1.w * w3.y;
            accA += nfA * e;
        }
        {
            const float2 w0 = *(const float2*)(WpL + ((mB      ) & 7u) * 128);
            const float2 w1 = *(const float2*)(WpL + ((mB >> 3 ) & 7u) * 128);
            const float2 w2 = *(const float2*)(WpL + ((mB >> 6 ) & 7u) * 128);
            const float2 w3 = *(const float2*)(WpL + ((mB >> 9 ) & 7u) * 128);
            const bool sr = (mB >> 12) & 1u;
            float e;
            e  = cB0.x * (sr ? w0.y : w0.x) + cB1.x * w0.y;
            e += cB0.y * (sr ? w1.y : w1.x) + cB1.y * w1.y;
            e += cB0.z * (sr ? w2.y : w2.x) + cB1.z * w2.y;
            e += cB0.w * (sr ? w3.y : w3.x) + cB1.w * w3.y;
            accB += nfB * e;
        }
    }
    out[pA * C_ + lane]       = accA;
    out[(pA + 1) * C_ + lane] = accB;
}

extern "C" void kernel_launch(void* const* d_in, const int* in_sizes, int n_in,
                              void* d_out, int out_size, void* d_ws, size_t ws_size,
                              hipStream_t stream) {
    const float* database = (const float*)d_in[0];
    const float* query    = (const float*)d_in[1];
    const int*   nn_index = (const int*)d_in[2];
    // d_in[3] = nn_count — unused by the reference computation
    const float* nn_dist  = (const float*)d_in[4];
    const float* feats    = (const float*)d_in[5];
    const float* filt     = (const float*)d_in[6];
    float* out = (float*)d_out;

    dim3 grid((B_ * M_) / PTS);   // 1024 blocks
    dim3 block(THREADS);
    hipLaunchKernelGGL(fuzzy_kernel, grid, block, 0, stream,
                       database, query, nn_index, nn_dist, feats, filt, out);
}

// Round 2
// 89.722 us; speedup vs baseline: 1.0299x; 1.0299x over previous
//
#include <hip/hip_runtime.h>

#define B_ 4
#define N_ 8192
#define M_ 2048
#define K_ 32
#define C_ 64
#define PTS 8
#define THREADS 256

typedef float f32x2 __attribute__((ext_vector_type(2)));
typedef float f32x4 __attribute__((ext_vector_type(4)));

__device__ __forceinline__ float clampf(float x, float lo, float hi) {
    return fminf(fmaxf(x, lo), hi);
}

__global__ __launch_bounds__(THREADS) void fuzzy_kernel(
    const float* __restrict__ database,
    const float* __restrict__ query,
    const int*   __restrict__ nn_index,
    const float* __restrict__ nn_dist,
    const float* __restrict__ feats,
    const float* __restrict__ filt,
    float*       __restrict__ out)
{
    // Dense per-(point,k) bin coefficients, chunked by azimuth index a:
    // g[a][pin][k] = float4(gamma[a*4+0..3])  (order: (e,r)=(0,0),(0,1),(1,0),(1,1))
    // Thread (pin,k) flat index == lane -> b128 writes at 16B lane stride (8/bank min).
    __shared__ f32x4 g[4][PTS][K_];        // 16 KB
    __shared__ int   rowofs[PTS][K_];      // feature-row element offsets (1 KB)

    const int tid  = threadIdx.x;
    const int lane = tid & 63;

    // ---- W[16][c] into registers, lane = channel c, paired for pk-fma ----
    f32x2 W2[8];
    #pragma unroll
    for (int m = 0; m < 8; ++m) {
        W2[m] = (f32x2){ filt[(2 * m) * C_ + lane], filt[(2 * m + 1) * C_ + lane] };
    }

    // ---- Phase A: one thread per (point-in-block, k) ----
    {
        const int pin = tid >> 5;                  // 0..7
        const int k   = tid & 31;                  // 0..31
        const int p   = blockIdx.x * PTS + pin;    // global point
        const int b   = p >> 11;                   // p / M_
        const float qx = query[p * 3 + 0];
        const float qy = query[p * 3 + 1];
        const float qz = query[p * 3 + 2];
        const int   idx  = nn_index[p * K_ + k];
        const float dist = nn_dist[p * K_ + k];
        const int   bidx = b * N_ + idx;
        rowofs[pin][k] = bidx * C_;
        const float x = database[bidx * 3 + 0] - qx;
        const float y = database[bidx * 3 + 1] - qy;
        const float z = database[bidx * 3 + 2] - qz;

        const float PI_F = 3.14159265358979323846f;
        const float SC   = 0.636619772367581343f;  // 2/pi
        float a_bin = (atan2f(y, x) + PI_F) * SC;                         // [0,4]
        float e_bin = acosf(clampf(z / (dist + 1e-8f), -1.0f, 1.0f)) * SC; // [0,2]
        float r_bin = clampf(dist * 20.0f, 0.0f, 1.999999f);
        float a_fl = floorf(a_bin), e_fl = floorf(e_bin), r_fl = floorf(r_bin);
        float a_fr = a_bin - a_fl, e_fr = e_bin - e_fl, r_fr = r_bin - r_fl;
        float ai = 1.0f - a_fr, ei = 1.0f - e_fr, ri = 1.0f - r_fr;
        int a_i = (int)a_fl, e_i = (int)e_fl, r_i = (int)r_fl;
        int a0 = a_i & 3, a1 = (a_i + 1) & 3;

        // Exact outer-product densification of the 8 corners:
        float E0 = (e_i < 1)  ? ei : 0.0f;
        float E1 = e_fr + ((e_i >= 1) ? ei : 0.0f);
        float R0 = (r_i == 0) ? ri : 0.0f;
        float R1 = r_fr + ((r_i == 1) ? ri : 0.0f);
        f32x4 er = (f32x4){ E0 * R0, E0 * R1, E1 * R0, E1 * R1 };
        #pragma unroll
        for (int j = 0; j < 4; ++j) {
            float Aj = (j == a0) ? ai : ((j == a1) ? a_fr : 0.0f);
            g[j][pin][k] = Aj * er;
        }
    }
    __syncthreads();

    // ---- Phase B: wave w -> points 2w, 2w+1; lane = channel ----
    const int wave = tid >> 6;
    const int pinA = wave * 2;
    const int pinB = pinA + 1;
    const int pA   = blockIdx.x * PTS + pinA;
    float accA = 0.0f, accB = 0.0f;

    #pragma unroll 8
    for (int k = 0; k < K_; ++k) {
        const f32x4 gA0 = g[0][pinA][k], gA1 = g[1][pinA][k];
        const f32x4 gA2 = g[2][pinA][k], gA3 = g[3][pinA][k];
        const f32x4 gB0 = g[0][pinB][k], gB1 = g[1][pinB][k];
        const f32x4 gB2 = g[2][pinB][k], gB3 = g[3][pinB][k];
        const float nfA = feats[rowofs[pinA][k] + lane];
        const float nfB = feats[rowofs[pinB][k] + lane];

        f32x2 sA = gA0.xy * W2[0] + gA0.zw * W2[1];
        sA += gA1.xy * W2[2] + gA1.zw * W2[3];
        sA += gA2.xy * W2[4] + gA2.zw * W2[5];
        sA += gA3.xy * W2[6] + gA3.zw * W2[7];
        f32x2 sB = gB0.xy * W2[0] + gB0.zw * W2[1];
        sB += gB1.xy * W2[2] + gB1.zw * W2[3];
        sB += gB2.xy * W2[4] + gB2.zw * W2[5];
        sB += gB3.xy * W2[6] + gB3.zw * W2[7];

        accA += nfA * (sA.x + sA.y);
        accB += nfB * (sB.x + sB.y);
    }
    out[pA * C_ + lane]       = accA;
    out[(pA + 1) * C_ + lane] = accB;
}

extern "C" void kernel_launch(void* const* d_in, const int* in_sizes, int n_in,
                              void* d_out, int out_size, void* d_ws, size_t ws_size,
                              hipStream_t stream) {
    const float* database = (const float*)d_in[0];
    const float* query    = (const float*)d_in[1];
    const int*   nn_index = (const int*)d_in[2];
    // d_in[3] = nn_count — unused by the reference computation
    const float* nn_dist  = (const float*)d_in[4];
    const float* feats    = (const float*)d_in[5];
    const float* filt     = (const float*)d_in[6];
    float* out = (float*)d_out;

    dim3 grid((B_ * M_) / PTS);   // 1024 blocks
    dim3 block(THREADS);
    hipLaunchKernelGGL(fuzzy_kernel, grid, block, 0, stream,
                       database, query, nn_index, nn_dist, feats, filt, out);
}

// Round 4
// 84.110 us; speedup vs baseline: 1.0987x; 1.0667x over previous
//
#include <hip/hip_runtime.h>

#define B_ 4
#define N_ 8192
#define M_ 2048
#define K_ 32
#define C_ 64
#define PTS 8
#define THREADS 256

typedef float     f32x4 __attribute__((ext_vector_type(4)));
typedef _Float16  h2    __attribute__((ext_vector_type(2)));
typedef _Float16  h8    __attribute__((ext_vector_type(8)));

__device__ __forceinline__ h2 pkrtz(float a, float b) {
    return __builtin_bit_cast(h2, __builtin_amdgcn_cvt_pkrtz(a, b));
}

#if defined(__has_builtin)
#if __has_builtin(__builtin_amdgcn_fdot2)
#define FDOT2(a, b, c) __builtin_amdgcn_fdot2((a), (b), (c), false)
#endif
#endif
#ifndef FDOT2
#define FDOT2(a, b, c) ((float)(a)[0] * (float)(b)[0] + (float)(a)[1] * (float)(b)[1] + (c))
#endif

__device__ __forceinline__ float clampf(float x, float lo, float hi) {
    return fminf(fmaxf(x, lo), hi);
}

__global__ __launch_bounds__(THREADS) void fuzzy_kernel(
    const float* __restrict__ database,
    const float* __restrict__ query,
    const int*   __restrict__ nn_index,
    const float* __restrict__ nn_dist,
    const float* __restrict__ feats,
    const float* __restrict__ filt,
    float*       __restrict__ out)
{
    // Per-(point,k) record: 16 fp16 trilinear coefficients gamma[t], t = a*4+e*2+r.
    // 32 B/record -> Phase B reads 2 broadcast ds_read_b128 per point per k.
    __shared__ h8 g[PTS * K_][2];   // 8 KB

    const int tid  = threadIdx.x;
    const int lane = tid & 63;

    // ---- W[16][c] -> fp16 pairs in registers, lane = channel c ----
    h2 Wh[8];
    #pragma unroll
    for (int m = 0; m < 8; ++m) {
        Wh[m] = pkrtz(filt[(2 * m) * C_ + lane], filt[(2 * m + 1) * C_ + lane]);
    }

    // ---- Phase A: one thread per (point-in-block, k) ----
    {
        const int pin = tid >> 5;                  // 0..7
        const int k   = tid & 31;                  // 0..31
        const int p   = blockIdx.x * PTS + pin;    // global point
        const int b   = p >> 11;                   // p / M_
        const float qx = query[p * 3 + 0];
        const float qy = query[p * 3 + 1];
        const float qz = query[p * 3 + 2];
        const int   idx  = nn_index[p * K_ + k];
        const float dist = nn_dist[p * K_ + k];
        const int   bidx = b * N_ + idx;
        const float x = database[bidx * 3 + 0] - qx;
        const float y = database[bidx * 3 + 1] - qy;
        const float z = database[bidx * 3 + 2] - qz;

        const float PI_F = 3.14159265358979323846f;
        const float SC   = 0.636619772367581343f;  // 2/pi
        float a_bin = (atan2f(y, x) + PI_F) * SC;                          // [0,4]
        float e_bin = acosf(clampf(z / (dist + 1e-8f), -1.0f, 1.0f)) * SC; // [0,2]
        float r_bin = clampf(dist * 20.0f, 0.0f, 1.999999f);
        float a_fl = floorf(a_bin), e_fl = floorf(e_bin), r_fl = floorf(r_bin);
        float a_fr = a_bin - a_fl, e_fr = e_bin - e_fl, r_fr = r_bin - r_fl;
        float ai = 1.0f - a_fr, ei = 1.0f - e_fr, ri = 1.0f - r_fr;
        int a_i = (int)a_fl, e_i = (int)e_fl, r_i = (int)r_fl;
        int a0 = a_i & 3, a1 = (a_i + 1) & 3;

        // Exact outer-product densification of the 8 corners:
        float E0 = (e_i < 1)  ? ei : 0.0f;
        float E1 = e_fr + ((e_i >= 1) ? ei : 0.0f);
        float R0 = (r_i == 0) ? ri : 0.0f;
        float R1 = r_fr + ((r_i == 1) ? ri : 0.0f);
        f32x4 er = (f32x4){ E0 * R0, E0 * R1, E1 * R0, E1 * R1 };

        float A[4];
        #pragma unroll
        for (int j = 0; j < 4; ++j)
            A[j] = (j == a0) ? ai : ((j == a1) ? a_fr : 0.0f);

        h2 q00 = pkrtz(A[0] * er.x, A[0] * er.y);
        h2 q01 = pkrtz(A[0] * er.z, A[0] * er.w);
        h2 q10 = pkrtz(A[1] * er.x, A[1] * er.y);
        h2 q11 = pkrtz(A[1] * er.z, A[1] * er.w);
        h2 q20 = pkrtz(A[2] * er.x, A[2] * er.y);
        h2 q21 = pkrtz(A[2] * er.z, A[2] * er.w);
        h2 q30 = pkrtz(A[3] * er.x, A[3] * er.y);
        h2 q31 = pkrtz(A[3] * er.z, A[3] * er.w);

        h8 lo = (h8){ q00[0], q00[1], q01[0], q01[1], q10[0], q10[1], q11[0], q11[1] };
        h8 hi = (h8){ q20[0], q20[1], q21[0], q21[1], q30[0], q30[1], q31[0], q31[1] };
        g[tid][0] = lo;
        g[tid][1] = hi;
    }
    __syncthreads();

    // ---- Phase B: wave w -> points 2w, 2w+1; lane = channel ----
    const int wave = __builtin_amdgcn_readfirstlane(tid >> 6);  // wave-uniform in SGPR
    const int pinA = wave * 2;
    const int pinB = pinA + 1;
    const int pA   = blockIdx.x * PTS + pinA;
    const int b    = pA >> 11;

    // Wave-uniform neighbor indices -> scalar loads; feats gather becomes
    // SGPR base + fixed lane offset (zero per-k VALU address math).
    const int* __restrict__ nnA = nn_index + pA * K_;
    const int* __restrict__ nnB = nnA + K_;
    const float* __restrict__ fb = feats + (size_t)b * (N_ * C_) + lane;

    float accA = 0.0f, accB = 0.0f;

    #pragma unroll 8
    for (int k = 0; k < K_; ++k) {
        const int rA = nnA[k];                 // s_load (uniform)
        const int rB = nnB[k];
        const h8 gA0 = g[pinA * K_ + k][0];    // broadcast ds_read_b128
        const h8 gA1 = g[pinA * K_ + k][1];
        const h8 gB0 = g[pinB * K_ + k][0];
        const h8 gB1 = g[pinB * K_ + k][1];
        const float nfA = fb[(size_t)rA << 6];
        const float nfB = fb[(size_t)rB << 6];

        float sA = 0.0f, sB = 0.0f;
        #pragma unroll
        for (int m = 0; m < 4; ++m) {
            h2 a0p = (h2){ gA0[2 * m], gA0[2 * m + 1] };
            h2 a1p = (h2){ gA1[2 * m], gA1[2 * m + 1] };
            h2 b0p = (h2){ gB0[2 * m], gB0[2 * m + 1] };
            h2 b1p = (h2){ gB1[2 * m], gB1[2 * m + 1] };
            sA = FDOT2(a0p, Wh[m], sA);
            sA = FDOT2(a1p, Wh[m + 4], sA);
            sB = FDOT2(b0p, Wh[m], sB);
            sB = FDOT2(b1p, Wh[m + 4], sB);
        }
        accA += nfA * sA;
        accB += nfB * sB;
    }
    out[pA * C_ + lane]       = accA;
    out[(pA + 1) * C_ + lane] = accB;
}

extern "C" void kernel_launch(void* const* d_in, const int* in_sizes, int n_in,
                              void* d_out, int out_size, void* d_ws, size_t ws_size,
                              hipStream_t stream) {
    const float* database = (const float*)d_in[0];
    const float* query    = (const float*)d_in[1];
    const int*   nn_index = (const int*)d_in[2];
    // d_in[3] = nn_count — unused by the reference computation
    const float* nn_dist  = (const float*)d_in[4];
    const float* feats    = (const float*)d_in[5];
    const float* filt     = (const float*)d_in[6];
    float* out = (float*)d_out;

    dim3 grid((B_ * M_) / PTS);   // 1024 blocks
    dim3 block(THREADS);
    hipLaunchKernelGGL(fuzzy_kernel, grid, block, 0, stream,
                       database, query, nn_index, nn_dist, feats, filt, out);
}